// Round 17
// baseline (176.465 us; speedup 1.0000x reference)
//
#include <hip/hip_runtime.h>
#include <hip/hip_bf16.h>

// LinearAttention (efficient attention): B=4 N=4096 D_MODEL=1024 H=16 DH=64
// Pipeline (4 launches):
//   prep(cvt + 2 transposes + zero ctx/ksum) -> gemm_qkv (256^2 barrier-lite;
//   kv blocks fuse CONTEXT in epilogue -> ctxT unnorm + ksum; k/v never hit HBM)
//   -> mid(w2 ++ q_softmax, fused launch) -> gemm_out.
//   attn_gemm eliminated via (qsm*ctx)*w_out == qsm*(ctx*w_out).
//   k-softmax max-pass eliminated (|k| <= ~6 -> exp f32-safe).

typedef unsigned short u16t;
typedef __bf16 bf16x8 __attribute__((ext_vector_type(8)));
typedef float f32x4 __attribute__((ext_vector_type(4)));
typedef unsigned short ushort8 __attribute__((ext_vector_type(8)));
typedef unsigned short u16x4 __attribute__((ext_vector_type(4)));

__device__ __forceinline__ u16t f2bf(float f) {
    union { float f; unsigned int u; } v; v.f = f;
    unsigned int r = v.u + 0x7fffu + ((v.u >> 16) & 1u);
    return (u16t)(r >> 16);
}
__device__ __forceinline__ float bf2f(u16t h) {
    union { unsigned int u; float f; } v; v.u = ((unsigned int)h) << 16;
    return v.f;
}

#define GLOAD_LDS16(gptr, lptr) \
    __builtin_amdgcn_global_load_lds((const __attribute__((address_space(1))) unsigned int*)(gptr), \
                                     (__attribute__((address_space(3))) unsigned int*)(lptr), 16, 0, 0)
#define SFENCE asm volatile("" ::: "memory")

// ---------------- prep: cvt x->bf16 (0..2047) | transpose wqkv (2048..5119)
//                  | transpose wout (5120..6143) | zero ctxT+ksum (6144..6211) --------
__global__ __launch_bounds__(256) void prep_kernel(const float* __restrict__ x, u16t* __restrict__ xb,
                                                   const float* __restrict__ w_qkv, u16t* __restrict__ wqkvT,
                                                   const float* __restrict__ w_out, u16t* __restrict__ woutT,
                                                   float* __restrict__ zbase) {
    int bid = blockIdx.x, t = threadIdx.x;
    if (bid < 2048) {
        int i = (bid * 256 + t) * 4;
        for (; i < 16777216; i += 2048 * 256 * 4) {
            float4 v = *(const float4*)(x + i);
            ushort4 o;
            o.x = f2bf(v.x); o.y = f2bf(v.y); o.z = f2bf(v.z); o.w = f2bf(v.w);
            *(ushort4*)(xb + i) = o;
        }
        return;
    }
    if (bid >= 6144) {
        float4* z = (float4*)zbase;
        int i = (bid - 6144) * 256 + t;
        for (; i < 69632; i += 68 * 256) z[i] = make_float4(0.f, 0.f, 0.f, 0.f);
        return;
    }
    __shared__ float tile[32][33];
    const float* in; u16t* out; int R, C, bx, by;
    if (bid < 5120) { in = w_qkv; out = wqkvT; R = 1024; C = 3072; int b2 = bid - 2048; bx = b2 % 96; by = b2 / 96; }
    else            { in = w_out; out = woutT; R = 1024; C = 1024; int b3 = bid - 5120; bx = b3 & 31; by = b3 >> 5; }
    int c0 = bx * 32, r0 = by * 32;
    int tx = t & 31, ty = t >> 5;
    for (int i = 0; i < 32; i += 8)
        tile[ty + i][tx] = in[(size_t)(r0 + ty + i) * C + c0 + tx];
    __syncthreads();
    for (int i = 0; i < 32; i += 8)
        out[(size_t)(c0 + ty + i) * R + r0 + tx] = f2bf(tile[tx][ty + i]);
}

// ---------------- 256x256 barrier-lite bf16 GEMM body: C = A * Bt^T ----------------
// A [M][lda] bf16 row-major, Bt [N][K] bf16 row-major. 512 threads = 8 waves (2Mx4N),
// per-wave 128x64, BK=64, LDS 128KB dbuf, T2 swizzle (conflict-free), XCD-bijective
// grid swizzle, 2 barriers/K-tile, counted vmcnt.
// KV=1 (gemm_qkv): bx<4 = q blocks; bx>=4 = kv-fused blocks (B rows {k,v} of 2 heads):
//   epilogue: ek=exp(acc[k]) -> LDS (granule-XOR swz) + ksum partials; v -> LDS;
//   2-head 64x64x256 product -> atomicAdd ctxT (unnormalized). No HBM k/v.
template<int OUTF32, int BIAS, int BATCHB, int KV>
__device__ __forceinline__ void gemm256_body(const u16t* __restrict__ A, const u16t* __restrict__ Bt,
                                             void* __restrict__ Cout, const float* __restrict__ bias,
                                             float* __restrict__ ksum, float* __restrict__ ctxT,
                                             int M, int N, int K, int NBX, int lda) {
    __shared__ __align__(16) u16t lds[65536];   // 128 KB
    const int t = threadIdx.x;
    const int l = t & 63, w = t >> 6;
    const int wm = w >> 2, wn = w & 3;

    int cpx = gridDim.x >> 3;
    int wg = ((int)blockIdx.x & 7) * cpx + ((int)blockIdx.x >> 3);
    int bx = wg % NBX, by = wg / NBX;
    const int m0 = by * 256, n0 = bx * 256;
    const int NT = K >> 6;
    if (BATCHB) Bt += (size_t)(by >> 4) << 20;

    const int colk0 = ((l >> 4) ^ (l & 7)) * 8;
    const int colk1 = colk0 ^ 32;
    const int abase = (wm * 32 + (l & 15)) * 64;
    const int bbase = 16384 + (wn >> 1) * 8192 + ((wn & 1) * 64 + (l & 15)) * 64;

    const int rr = w * 8 + (l >> 3);
    const int coloff = ((l ^ (l >> 3)) & 7) * 8;
    const int rowA = rr + ((rr >= 32) ? 96 : 0);
    const u16t* pa_st = A + (size_t)(m0 + rowA) * lda + coloff;
    int rb0, rb1;
    if (KV && bx >= 4) { int hp = bx - 4; rb0 = 1024 + hp * 128; rb1 = 2048 + hp * 128; }
    else               { rb0 = n0; rb1 = n0 + 128; }
    const u16t* pb0 = Bt + (size_t)(rb0 + rr) * K + coloff;
    const u16t* pb1 = Bt + (size_t)(rb1 + rr) * K + coloff;
    const int so = w * 512;

#define SPAIR(qq, kto, pb) do { \
    size_t k64_ = (size_t)(kto) * 64; \
    if ((qq) == 0) { \
        GLOAD_LDS16(pb0 + k64_,                  &lds[(pb) * 32768 + 16384 + so]); \
        GLOAD_LDS16(pb0 + k64_ + (size_t)64 * K, &lds[(pb) * 32768 + 20480 + so]); \
    } else if ((qq) == 1) { \
        GLOAD_LDS16(pb1 + k64_,                  &lds[(pb) * 32768 + 24576 + so]); \
        GLOAD_LDS16(pb1 + k64_ + (size_t)64 * K, &lds[(pb) * 32768 + 28672 + so]); \
    } else if ((qq) == 2) { \
        GLOAD_LDS16(pa_st + k64_,                    &lds[(pb) * 32768 + so]); \
        GLOAD_LDS16(pa_st + k64_ + (size_t)32 * lda, &lds[(pb) * 32768 + 4096 + so]); \
    } else { \
        GLOAD_LDS16(pa_st + k64_ + (size_t)64 * lda, &lds[(pb) * 32768 + 8192 + so]); \
        GLOAD_LDS16(pa_st + k64_ + (size_t)96 * lda, &lds[(pb) * 32768 + 12288 + so]); \
    } \
} while (0)

    f32x4 acc[8][4] = {};

    SPAIR(0, 0, 0); SPAIR(1, 0, 0); SPAIR(2, 0, 0);
    SFENCE;
    SPAIR(3, 0, 0);

    for (int kt = 0; kt < NT; ++kt) {
        const int p = kt & 1;
        const bool sn = (kt + 1 < NT);
        const u16t* lA = &lds[p * 32768];

        asm volatile("s_waitcnt vmcnt(2)" ::: "memory");
        __builtin_amdgcn_s_barrier();

        bf16x8 bfr[4][2];
#pragma unroll
        for (int ni = 0; ni < 4; ++ni) {
            bfr[ni][0] = *(const bf16x8*)&lA[bbase + ni * 1024 + colk0];
            bfr[ni][1] = *(const bf16x8*)&lA[bbase + ni * 1024 + colk1];
        }
        bf16x8 af1[2][2][2];
#pragma unroll
        for (int g = 0; g < 2; ++g) {
            af1[g][0][0] = *(const bf16x8*)&lA[g * 4096 + abase + colk0];
            af1[g][0][1] = *(const bf16x8*)&lA[g * 4096 + abase + colk1];
            af1[g][1][0] = *(const bf16x8*)&lA[g * 4096 + abase + 1024 + colk0];
            af1[g][1][1] = *(const bf16x8*)&lA[g * 4096 + abase + 1024 + colk1];
        }
        if (sn) { SPAIR(0, kt + 1, p ^ 1); SPAIR(1, kt + 1, p ^ 1); SPAIR(2, kt + 1, p ^ 1); }
        __builtin_amdgcn_s_setprio(1);
#pragma unroll
        for (int g = 0; g < 2; ++g)
#pragma unroll
            for (int dm = 0; dm < 2; ++dm)
#pragma unroll
                for (int ni = 0; ni < 4; ++ni)
#pragma unroll
                    for (int kk = 0; kk < 2; ++kk)
                        acc[g * 2 + dm][ni] = __builtin_amdgcn_mfma_f32_16x16x32_bf16(
                            af1[g][dm][kk], bfr[ni][kk], acc[g * 2 + dm][ni], 0, 0, 0);
        __builtin_amdgcn_s_setprio(0);

        if (sn) asm volatile("s_waitcnt vmcnt(6)" ::: "memory");
        else    asm volatile("s_waitcnt vmcnt(0)" ::: "memory");
        __builtin_amdgcn_s_barrier();

        bf16x8 af2[2][2][2];
#pragma unroll
        for (int g = 0; g < 2; ++g) {
            af2[g][0][0] = *(const bf16x8*)&lA[(g + 2) * 4096 + abase + colk0];
            af2[g][0][1] = *(const bf16x8*)&lA[(g + 2) * 4096 + abase + colk1];
            af2[g][1][0] = *(const bf16x8*)&lA[(g + 2) * 4096 + abase + 1024 + colk0];
            af2[g][1][1] = *(const bf16x8*)&lA[(g + 2) * 4096 + abase + 1024 + colk1];
        }
        if (sn) SPAIR(3, kt + 1, p ^ 1);
        __builtin_amdgcn_s_setprio(1);
#pragma unroll
        for (int g = 0; g < 2; ++g)
#pragma unroll
            for (int dm = 0; dm < 2; ++dm)
#pragma unroll
                for (int ni = 0; ni < 4; ++ni)
#pragma unroll
                    for (int kk = 0; kk < 2; ++kk)
                        acc[4 + g * 2 + dm][ni] = __builtin_amdgcn_mfma_f32_16x16x32_bf16(
                            af2[g][dm][kk], bfr[ni][kk], acc[4 + g * 2 + dm][ni], 0, 0, 0);
        __builtin_amdgcn_s_setprio(0);
    }
#undef SPAIR

    if (KV && bx >= 4) {
        // ---- fused context epilogue (2 heads) ----
        const int hp = bx - 4;
        const int bb = by >> 4;
        __syncthreads();                       // protect other waves' last-tile ds_reads
        u16t* ekT = lds;                       // [128 d'][256 r], granule-XOR swizzled
        u16t* vT  = lds + 32768;               // [128 e'][256 r]
#define EADDR(dp, r) ((dp) * 256 + ((r) ^ (((dp) & 15) << 2)))
        if (wn < 2) {
#pragma unroll
            for (int ni = 0; ni < 4; ++ni) {
                int dp = wn * 64 + ni * 16 + (l & 15);
                float se = 0.f;
#pragma unroll
                for (int mi = 0; mi < 8; ++mi) {
                    int r0 = wm * 128 + mi * 16 + ((l >> 4) << 2);
                    u16x4 pk;
#pragma unroll
                    for (int j = 0; j < 4; ++j) { float e = __expf(acc[mi][ni][j]); se += e; pk[j] = f2bf(e); }
                    *(u16x4*)&ekT[EADDR(dp, r0)] = pk;
                }
                se += __shfl_xor(se, 16);
                se += __shfl_xor(se, 32);
                if ((l >> 4) == 0)
                    atomicAdd(&ksum[bb * 1024 + hp * 128 + dp], se);
            }
        } else {
#pragma unroll
            for (int ni = 0; ni < 4; ++ni) {
                int ep = (wn - 2) * 64 + ni * 16 + (l & 15);
#pragma unroll
                for (int mi = 0; mi < 8; ++mi) {
                    int r0 = wm * 128 + mi * 16 + ((l >> 4) << 2);
                    u16x4 pv;
#pragma unroll
                    for (int j = 0; j < 4; ++j) pv[j] = f2bf(acc[mi][ni][j]);
                    *(u16x4*)&vT[EADDR(ep, r0)] = pv;
                }
            }
        }
        __syncthreads();
        // head-product: wave w -> head = w>>2, tn = w&3; tiles tm 0..3; K = 256 rows
        const int head = w >> 2, tn = w & 3;
        const int dp2 = head * 64 + tn * 16 + (l & 15);
        const int sb2 = (dp2 & 15) << 2;
        f32x4 acc2[4] = {};
#pragma unroll
        for (int ks = 0; ks < 8; ++ks) {
            int rk = ks * 32 + ((l >> 4) << 3);
            union { u16x4 h[2]; bf16x8 v; } bu;
            bu.h[0] = *(const u16x4*)&ekT[dp2 * 256 + (rk ^ sb2)];
            bu.h[1] = *(const u16x4*)&ekT[dp2 * 256 + ((rk + 4) ^ sb2)];
#pragma unroll
            for (int tm = 0; tm < 4; ++tm) {
                int ep = head * 64 + tm * 16 + (l & 15);
                int sa = (ep & 15) << 2;
                union { u16x4 h[2]; bf16x8 v; } au;
                au.h[0] = *(const u16x4*)&vT[ep * 256 + (rk ^ sa)];
                au.h[1] = *(const u16x4*)&vT[ep * 256 + ((rk + 4) ^ sa)];
                acc2[tm] = __builtin_amdgcn_mfma_f32_16x16x32_bf16(au.v, bu.v, acc2[tm], 0, 0, 0);
            }
        }
#undef EADDR
        int bh = bb * 16 + hp * 2 + head;
#pragma unroll
        for (int tm = 0; tm < 4; ++tm) {
            int e = tm * 16 + ((l >> 4) << 2);
            int dd = tn * 16 + (l & 15);
#pragma unroll
            for (int j = 0; j < 4; ++j)
                atomicAdd(&ctxT[(size_t)bh * 4096 + (e + j) * 64 + dd], acc2[tm][j]);
        }
    } else {
        // ---- generic epilogue ----
#pragma unroll
        for (int mi = 0; mi < 8; ++mi) {
            int row = m0 + wm * 128 + mi * 16 + ((l >> 4) << 2);
#pragma unroll
            for (int ni = 0; ni < 4; ++ni) {
                int col = n0 + wn * 64 + ni * 16 + (l & 15);
                float bv = BIAS ? bias[col] : 0.f;
#pragma unroll
                for (int j = 0; j < 4; ++j) {
                    float v = acc[mi][ni][j] + bv;
                    if (OUTF32) ((float*)Cout)[(size_t)(row + j) * N + col] = v;
                    else        ((u16t*)Cout)[(size_t)(row + j) * N + col] = f2bf(v);
                }
            }
        }
    }
}

// GEMM1: [16384,1024] x [1024,3072]; q cols -> qkv; kv blocks -> ctxT/ksum directly
__global__ __launch_bounds__(512, 2) void gemm_qkv(const u16t* __restrict__ A, const u16t* __restrict__ Bt,
                                                   u16t* __restrict__ C, float* __restrict__ ksum,
                                                   float* __restrict__ ctxT) {
    gemm256_body<0, 0, 0, 1>(A, Bt, C, nullptr, ksum, ctxT, 16384, 3072, 1024, 12, 1024);
}

// final: out[b] = qsm[b] (lda=3072, cols 0..1023) x W2T[b]^T + bias, f32
__global__ __launch_bounds__(512, 2) void gemm_out(const u16t* __restrict__ A, const u16t* __restrict__ Bt,
                                                   float* __restrict__ C, const float* __restrict__ bias) {
    gemm256_body<1, 1, 1, 0>(A, Bt, C, bias, nullptr, nullptr, 16384, 1024, 1024, 4, 3072);
}

// ---------------- mid: w2 (blocks 0..255) ++ q_softmax (256..1279) ----------------
// Independent: w2 reads ctxT/ksum/woutT -> w2t; qsm rewrites q third of qkv in place.
// w2: W2T[b][j][h*64+d] = sum_e (ctxT[bh][e][d]/ksum[d]) * woutT[j][h*64+e].
// qsm: in-place softmax over d=64 per row-head, * SCALE, 8-lane groups.
__global__ __launch_bounds__(256) void mid_kernel(const float* __restrict__ ctxT,
                                                  const float* __restrict__ ksum,
                                                  const u16t* __restrict__ woutT,
                                                  u16t* __restrict__ w2t,
                                                  u16t* __restrict__ qkv) {
    int bid = blockIdx.x, t = threadIdx.x;
    if (bid < 256) {
        int bh = bid >> 2, jc = bid & 3;
        int b = bh >> 4, h = bh & 15;
        __shared__ u16t cb[64][72];
        __shared__ u16t wl[256][72];
        float ginv = 1.0f / ksum[b * 1024 + h * 64 + (t & 63)];
#pragma unroll
        for (int i = 0; i < 16; i++) {
            int f = t + 256 * i;
            cb[f & 63][f >> 6] = f2bf(ctxT[(size_t)bh * 4096 + f] * ginv);
        }
#pragma unroll
        for (int i = 0; i < 8; i++) {
            int f = t + 256 * i;
            int r = f >> 3, q = f & 7;
            *(uint4*)(&wl[r][q * 8]) = *(const uint4*)(&woutT[(size_t)(jc * 256 + r) * 1024 + h * 64 + q * 8]);
        }
        __syncthreads();
        int l = t & 63, w = t >> 6;
        f32x4 acc[4][4] = {};
#pragma unroll
        for (int kk = 0; kk < 2; kk++) {
            bf16x8 af[4], bfr[4];
#pragma unroll
            for (int mt = 0; mt < 4; mt++)
                af[mt] = *(const bf16x8*)&wl[w * 64 + mt * 16 + (l & 15)][(l >> 4) * 8 + kk * 32];
#pragma unroll
            for (int nt = 0; nt < 4; nt++)
                bfr[nt] = *(const bf16x8*)&cb[nt * 16 + (l & 15)][(l >> 4) * 8 + kk * 32];
#pragma unroll
            for (int mt = 0; mt < 4; mt++)
#pragma unroll
                for (int nt = 0; nt < 4; nt++)
                    acc[mt][nt] = __builtin_amdgcn_mfma_f32_16x16x32_bf16(af[mt], bfr[nt], acc[mt][nt], 0, 0, 0);
        }
#pragma unroll
        for (int mt = 0; mt < 4; mt++) {
            int j = jc * 256 + w * 64 + mt * 16 + ((l >> 4) << 2);
#pragma unroll
            for (int nt = 0; nt < 4; nt++) {
                int dd = nt * 16 + (l & 15);
#pragma unroll
                for (int jj = 0; jj < 4; jj++)
                    w2t[((size_t)b << 20) + (size_t)(j + jj) * 1024 + h * 64 + dd] = f2bf(acc[mt][nt][jj]);
            }
        }
        return;
    }
    // ---- q softmax rows ----
    int qb = bid - 256;
#pragma unroll
    for (int it = 0; it < 8; ++it) {
        int r = qb * 256 + it * 32 + (t >> 3);
        size_t addr = (size_t)(r >> 4) * 3072 + (r & 15) * 64 + (t & 7) * 8;
        ushort8 ch = *(const ushort8*)(&qkv[addr]);
        float v0 = bf2f(ch[0]), v1 = bf2f(ch[1]), v2 = bf2f(ch[2]), v3 = bf2f(ch[3]);
        float v4 = bf2f(ch[4]), v5 = bf2f(ch[5]), v6 = bf2f(ch[6]), v7 = bf2f(ch[7]);
        float m = fmaxf(fmaxf(fmaxf(v0, v1), fmaxf(v2, v3)), fmaxf(fmaxf(v4, v5), fmaxf(v6, v7)));
        m = fmaxf(m, __shfl_xor(m, 1)); m = fmaxf(m, __shfl_xor(m, 2)); m = fmaxf(m, __shfl_xor(m, 4));
        float e0 = __expf(v0 - m), e1 = __expf(v1 - m), e2 = __expf(v2 - m), e3 = __expf(v3 - m);
        float e4 = __expf(v4 - m), e5 = __expf(v5 - m), e6 = __expf(v6 - m), e7 = __expf(v7 - m);
        float s = e0 + e1 + e2 + e3 + e4 + e5 + e6 + e7;
        s += __shfl_xor(s, 1); s += __shfl_xor(s, 2); s += __shfl_xor(s, 4);
        float inv = 0.125f / s;
        ushort8 o;
        o[0] = f2bf(e0 * inv); o[1] = f2bf(e1 * inv); o[2] = f2bf(e2 * inv); o[3] = f2bf(e3 * inv);
        o[4] = f2bf(e4 * inv); o[5] = f2bf(e5 * inv); o[6] = f2bf(e6 * inv); o[7] = f2bf(e7 * inv);
        *(ushort8*)(&qkv[addr]) = o;
    }
}

// ---------------- launch ----------------

extern "C" void kernel_launch(void* const* d_in, const int* in_sizes, int n_in,
                              void* d_out, int out_size, void* d_ws, size_t ws_size,
                              hipStream_t stream) {
    const float* x     = (const float*)d_in[0];
    const float* w_qkv = (const float*)d_in[1];
    const float* w_out = (const float*)d_in[2];
    const float* b_out = (const float*)d_in[3];
    float* out = (float*)d_out;
    char* ws = (char*)d_ws;

    size_t o_xb    = 0;                       // 16384*1024*2 = 33554432 (reused as w2t)
    size_t o_wqkvT = 33554432;                // 3072*1024*2  = 6291456
    size_t o_woutT = 39845888;                // 1024*1024*2  = 2097152
    size_t o_qkv   = 41943040;                // 16384*3072*2 (q third used)
    size_t o_ctx   = 142606336;               // 64*64*64*4   = 1048576
    size_t o_ksum  = 143654912;               // 65536 (contiguous after ctx for zeroing)
    size_t needed  = 143720448;
    if (ws_size < needed) return;

    u16t* xb     = (u16t*)(ws + o_xb);
    u16t* w2t    = (u16t*)(ws + o_xb);        // reuse (xb dead after gemm_qkv)
    u16t* wqkvT  = (u16t*)(ws + o_wqkvT);
    u16t* woutT  = (u16t*)(ws + o_woutT);
    u16t* qkvb   = (u16t*)(ws + o_qkv);
    float* ctxT  = (float*)(ws + o_ctx);
    float* ksum  = (float*)(ws + o_ksum);

    // cvt + both weight transposes + zero(ctxT,ksum), one launch
    prep_kernel<<<6212, 256, 0, stream>>>(x, xb, w_qkv, wqkvT, w_out, woutT, ctxT);

    // GEMM1 + fused context: q cols -> qkv; kv blocks -> ctxT (unnorm) + ksum
    gemm_qkv<<<768, 512, 0, stream>>>(xb, wqkvT, qkvb, ksum, ctxT);

    // w2 (256 blocks) ++ q softmax (1024 blocks), one launch
    mid_kernel<<<1280, 256, 0, stream>>>(ctxT, ksum, woutT, w2t, qkvb);

    // out[b] = qsm[b] x W2T[b]^T + bias (f32)
    gemm_out<<<256, 512, 0, stream>>>(qkvb, w2t, out, b_out);
}

// Round 18
// 175.301 us; speedup vs baseline: 1.0066x; 1.0066x over previous
//
#include <hip/hip_runtime.h>
#include <hip/hip_bf16.h>

// LinearAttention (efficient attention): B=4 N=4096 D_MODEL=1024 H=16 DH=64
// Pipeline (5 launches):
//   prep(cvt + 2 transposes + zero ctx/ksum) -> gemm_qkv (256^2 barrier-lite;
//   kv blocks fuse CONTEXT in epilogue: ek=exp(k-acc), ctx_partial = v^T ek via
//   LDS-restaged MFMA, atomicAdd -> ctxT unnormalized + ksum partials; k/v never
//   written to HBM) -> w2 (normalizes ctx by 1/ksum at staging) -> q_softmax ->
//   gemm_out.  attn_gemm eliminated via (qsm*ctx)*w_out == qsm*(ctx*w_out).
//   k-softmax max-pass eliminated (|k| <= ~6 -> exp f32-safe).
// r17's mid-merge (w2 ++ qsm one launch) REVERTED: +3.6us (w2's 45KB LDS capped
// qsm co-residency). r16 configuration = measured best (172.9us).

typedef unsigned short u16t;
typedef __bf16 bf16x8 __attribute__((ext_vector_type(8)));
typedef float f32x4 __attribute__((ext_vector_type(4)));
typedef unsigned short ushort8 __attribute__((ext_vector_type(8)));
typedef unsigned short u16x4 __attribute__((ext_vector_type(4)));

__device__ __forceinline__ u16t f2bf(float f) {
    union { float f; unsigned int u; } v; v.f = f;
    unsigned int r = v.u + 0x7fffu + ((v.u >> 16) & 1u);
    return (u16t)(r >> 16);
}
__device__ __forceinline__ float bf2f(u16t h) {
    union { unsigned int u; float f; } v; v.u = ((unsigned int)h) << 16;
    return v.f;
}

#define GLOAD_LDS16(gptr, lptr) \
    __builtin_amdgcn_global_load_lds((const __attribute__((address_space(1))) unsigned int*)(gptr), \
                                     (__attribute__((address_space(3))) unsigned int*)(lptr), 16, 0, 0)
#define SFENCE asm volatile("" ::: "memory")

// ---------------- prep: cvt x->bf16 (0..2047) | transpose wqkv (2048..5119)
//                  | transpose wout (5120..6143) | zero ctxT+ksum (6144..6211) --------
__global__ __launch_bounds__(256) void prep_kernel(const float* __restrict__ x, u16t* __restrict__ xb,
                                                   const float* __restrict__ w_qkv, u16t* __restrict__ wqkvT,
                                                   const float* __restrict__ w_out, u16t* __restrict__ woutT,
                                                   float* __restrict__ zbase) {
    int bid = blockIdx.x, t = threadIdx.x;
    if (bid < 2048) {
        int i = (bid * 256 + t) * 4;
        for (; i < 16777216; i += 2048 * 256 * 4) {
            float4 v = *(const float4*)(x + i);
            ushort4 o;
            o.x = f2bf(v.x); o.y = f2bf(v.y); o.z = f2bf(v.z); o.w = f2bf(v.w);
            *(ushort4*)(xb + i) = o;
        }
        return;
    }
    if (bid >= 6144) {
        float4* z = (float4*)zbase;
        int i = (bid - 6144) * 256 + t;
        for (; i < 69632; i += 68 * 256) z[i] = make_float4(0.f, 0.f, 0.f, 0.f);
        return;
    }
    __shared__ float tile[32][33];
    const float* in; u16t* out; int R, C, bx, by;
    if (bid < 5120) { in = w_qkv; out = wqkvT; R = 1024; C = 3072; int b2 = bid - 2048; bx = b2 % 96; by = b2 / 96; }
    else            { in = w_out; out = woutT; R = 1024; C = 1024; int b3 = bid - 5120; bx = b3 & 31; by = b3 >> 5; }
    int c0 = bx * 32, r0 = by * 32;
    int tx = t & 31, ty = t >> 5;
    for (int i = 0; i < 32; i += 8)
        tile[ty + i][tx] = in[(size_t)(r0 + ty + i) * C + c0 + tx];
    __syncthreads();
    for (int i = 0; i < 32; i += 8)
        out[(size_t)(c0 + ty + i) * R + r0 + tx] = f2bf(tile[tx][ty + i]);
}

// ---------------- 256x256 barrier-lite bf16 GEMM body: C = A * Bt^T ----------------
// A [M][lda] bf16 row-major, Bt [N][K] bf16 row-major. 512 threads = 8 waves (2Mx4N),
// per-wave 128x64, BK=64, LDS 128KB dbuf, T2 swizzle (conflict-free), XCD-bijective
// grid swizzle, 2 barriers/K-tile, counted vmcnt.
// KV=1 (gemm_qkv): bx<4 = q blocks; bx>=4 = kv-fused blocks (B rows {k,v} of 2 heads):
//   epilogue: ek=exp(acc[k]) -> LDS (granule-XOR swz) + ksum partials; v -> LDS;
//   2-head 64x64x256 product -> atomicAdd ctxT (unnormalized). No HBM k/v.
template<int OUTF32, int BIAS, int BATCHB, int KV>
__device__ __forceinline__ void gemm256_body(const u16t* __restrict__ A, const u16t* __restrict__ Bt,
                                             void* __restrict__ Cout, const float* __restrict__ bias,
                                             float* __restrict__ ksum, float* __restrict__ ctxT,
                                             int M, int N, int K, int NBX, int lda) {
    __shared__ __align__(16) u16t lds[65536];   // 128 KB
    const int t = threadIdx.x;
    const int l = t & 63, w = t >> 6;
    const int wm = w >> 2, wn = w & 3;

    int cpx = gridDim.x >> 3;
    int wg = ((int)blockIdx.x & 7) * cpx + ((int)blockIdx.x >> 3);
    int bx = wg % NBX, by = wg / NBX;
    const int m0 = by * 256, n0 = bx * 256;
    const int NT = K >> 6;
    if (BATCHB) Bt += (size_t)(by >> 4) << 20;

    const int colk0 = ((l >> 4) ^ (l & 7)) * 8;
    const int colk1 = colk0 ^ 32;
    const int abase = (wm * 32 + (l & 15)) * 64;
    const int bbase = 16384 + (wn >> 1) * 8192 + ((wn & 1) * 64 + (l & 15)) * 64;

    const int rr = w * 8 + (l >> 3);
    const int coloff = ((l ^ (l >> 3)) & 7) * 8;
    const int rowA = rr + ((rr >= 32) ? 96 : 0);
    const u16t* pa_st = A + (size_t)(m0 + rowA) * lda + coloff;
    int rb0, rb1;
    if (KV && bx >= 4) { int hp = bx - 4; rb0 = 1024 + hp * 128; rb1 = 2048 + hp * 128; }
    else               { rb0 = n0; rb1 = n0 + 128; }
    const u16t* pb0 = Bt + (size_t)(rb0 + rr) * K + coloff;
    const u16t* pb1 = Bt + (size_t)(rb1 + rr) * K + coloff;
    const int so = w * 512;

#define SPAIR(qq, kto, pb) do { \
    size_t k64_ = (size_t)(kto) * 64; \
    if ((qq) == 0) { \
        GLOAD_LDS16(pb0 + k64_,                  &lds[(pb) * 32768 + 16384 + so]); \
        GLOAD_LDS16(pb0 + k64_ + (size_t)64 * K, &lds[(pb) * 32768 + 20480 + so]); \
    } else if ((qq) == 1) { \
        GLOAD_LDS16(pb1 + k64_,                  &lds[(pb) * 32768 + 24576 + so]); \
        GLOAD_LDS16(pb1 + k64_ + (size_t)64 * K, &lds[(pb) * 32768 + 28672 + so]); \
    } else if ((qq) == 2) { \
        GLOAD_LDS16(pa_st + k64_,                    &lds[(pb) * 32768 + so]); \
        GLOAD_LDS16(pa_st + k64_ + (size_t)32 * lda, &lds[(pb) * 32768 + 4096 + so]); \
    } else { \
        GLOAD_LDS16(pa_st + k64_ + (size_t)64 * lda, &lds[(pb) * 32768 + 8192 + so]); \
        GLOAD_LDS16(pa_st + k64_ + (size_t)96 * lda, &lds[(pb) * 32768 + 12288 + so]); \
    } \
} while (0)

    f32x4 acc[8][4] = {};

    SPAIR(0, 0, 0); SPAIR(1, 0, 0); SPAIR(2, 0, 0);
    SFENCE;
    SPAIR(3, 0, 0);

    for (int kt = 0; kt < NT; ++kt) {
        const int p = kt & 1;
        const bool sn = (kt + 1 < NT);
        const u16t* lA = &lds[p * 32768];

        asm volatile("s_waitcnt vmcnt(2)" ::: "memory");
        __builtin_amdgcn_s_barrier();

        bf16x8 bfr[4][2];
#pragma unroll
        for (int ni = 0; ni < 4; ++ni) {
            bfr[ni][0] = *(const bf16x8*)&lA[bbase + ni * 1024 + colk0];
            bfr[ni][1] = *(const bf16x8*)&lA[bbase + ni * 1024 + colk1];
        }
        bf16x8 af1[2][2][2];
#pragma unroll
        for (int g = 0; g < 2; ++g) {
            af1[g][0][0] = *(const bf16x8*)&lA[g * 4096 + abase + colk0];
            af1[g][0][1] = *(const bf16x8*)&lA[g * 4096 + abase + colk1];
            af1[g][1][0] = *(const bf16x8*)&lA[g * 4096 + abase + 1024 + colk0];
            af1[g][1][1] = *(const bf16x8*)&lA[g * 4096 + abase + 1024 + colk1];
        }
        if (sn) { SPAIR(0, kt + 1, p ^ 1); SPAIR(1, kt + 1, p ^ 1); SPAIR(2, kt + 1, p ^ 1); }
        __builtin_amdgcn_s_setprio(1);
#pragma unroll
        for (int g = 0; g < 2; ++g)
#pragma unroll
            for (int dm = 0; dm < 2; ++dm)
#pragma unroll
                for (int ni = 0; ni < 4; ++ni)
#pragma unroll
                    for (int kk = 0; kk < 2; ++kk)
                        acc[g * 2 + dm][ni] = __builtin_amdgcn_mfma_f32_16x16x32_bf16(
                            af1[g][dm][kk], bfr[ni][kk], acc[g * 2 + dm][ni], 0, 0, 0);
        __builtin_amdgcn_s_setprio(0);

        if (sn) asm volatile("s_waitcnt vmcnt(6)" ::: "memory");
        else    asm volatile("s_waitcnt vmcnt(0)" ::: "memory");
        __builtin_amdgcn_s_barrier();

        bf16x8 af2[2][2][2];
#pragma unroll
        for (int g = 0; g < 2; ++g) {
            af2[g][0][0] = *(const bf16x8*)&lA[(g + 2) * 4096 + abase + colk0];
            af2[g][0][1] = *(const bf16x8*)&lA[(g + 2) * 4096 + abase + colk1];
            af2[g][1][0] = *(const bf16x8*)&lA[(g + 2) * 4096 + abase + 1024 + colk0];
            af2[g][1][1] = *(const bf16x8*)&lA[(g + 2) * 4096 + abase + 1024 + colk1];
        }
        if (sn) SPAIR(3, kt + 1, p ^ 1);
        __builtin_amdgcn_s_setprio(1);
#pragma unroll
        for (int g = 0; g < 2; ++g)
#pragma unroll
            for (int dm = 0; dm < 2; ++dm)
#pragma unroll
                for (int ni = 0; ni < 4; ++ni)
#pragma unroll
                    for (int kk = 0; kk < 2; ++kk)
                        acc[4 + g * 2 + dm][ni] = __builtin_amdgcn_mfma_f32_16x16x32_bf16(
                            af2[g][dm][kk], bfr[ni][kk], acc[4 + g * 2 + dm][ni], 0, 0, 0);
        __builtin_amdgcn_s_setprio(0);
    }
#undef SPAIR

    if (KV && bx >= 4) {
        // ---- fused context epilogue (2 heads) ----
        const int hp = bx - 4;
        const int bb = by >> 4;
        __syncthreads();                       // protect other waves' last-tile ds_reads
        u16t* ekT = lds;                       // [128 d'][256 r], granule-XOR swizzled
        u16t* vT  = lds + 32768;               // [128 e'][256 r]
#define EADDR(dp, r) ((dp) * 256 + ((r) ^ (((dp) & 15) << 2)))
        if (wn < 2) {
#pragma unroll
            for (int ni = 0; ni < 4; ++ni) {
                int dp = wn * 64 + ni * 16 + (l & 15);
                float se = 0.f;
#pragma unroll
                for (int mi = 0; mi < 8; ++mi) {
                    int r0 = wm * 128 + mi * 16 + ((l >> 4) << 2);
                    u16x4 pk;
#pragma unroll
                    for (int j = 0; j < 4; ++j) { float e = __expf(acc[mi][ni][j]); se += e; pk[j] = f2bf(e); }
                    *(u16x4*)&ekT[EADDR(dp, r0)] = pk;
                }
                se += __shfl_xor(se, 16);
                se += __shfl_xor(se, 32);
                if ((l >> 4) == 0)
                    atomicAdd(&ksum[bb * 1024 + hp * 128 + dp], se);
            }
        } else {
#pragma unroll
            for (int ni = 0; ni < 4; ++ni) {
                int ep = (wn - 2) * 64 + ni * 16 + (l & 15);
#pragma unroll
                for (int mi = 0; mi < 8; ++mi) {
                    int r0 = wm * 128 + mi * 16 + ((l >> 4) << 2);
                    u16x4 pv;
#pragma unroll
                    for (int j = 0; j < 4; ++j) pv[j] = f2bf(acc[mi][ni][j]);
                    *(u16x4*)&vT[EADDR(ep, r0)] = pv;
                }
            }
        }
        __syncthreads();
        // head-product: wave w -> head = w>>2, tn = w&3; tiles tm 0..3; K = 256 rows
        const int head = w >> 2, tn = w & 3;
        const int dp2 = head * 64 + tn * 16 + (l & 15);
        const int sb2 = (dp2 & 15) << 2;
        f32x4 acc2[4] = {};
#pragma unroll
        for (int ks = 0; ks < 8; ++ks) {
            int rk = ks * 32 + ((l >> 4) << 3);
            union { u16x4 h[2]; bf16x8 v; } bu;
            bu.h[0] = *(const u16x4*)&ekT[dp2 * 256 + (rk ^ sb2)];
            bu.h[1] = *(const u16x4*)&ekT[dp2 * 256 + ((rk + 4) ^ sb2)];
#pragma unroll
            for (int tm = 0; tm < 4; ++tm) {
                int ep = head * 64 + tm * 16 + (l & 15);
                int sa = (ep & 15) << 2;
                union { u16x4 h[2]; bf16x8 v; } au;
                au.h[0] = *(const u16x4*)&vT[ep * 256 + (rk ^ sa)];
                au.h[1] = *(const u16x4*)&vT[ep * 256 + ((rk + 4) ^ sa)];
                acc2[tm] = __builtin_amdgcn_mfma_f32_16x16x32_bf16(au.v, bu.v, acc2[tm], 0, 0, 0);
            }
        }
#undef EADDR
        int bh = bb * 16 + hp * 2 + head;
#pragma unroll
        for (int tm = 0; tm < 4; ++tm) {
            int e = tm * 16 + ((l >> 4) << 2);
            int dd = tn * 16 + (l & 15);
#pragma unroll
            for (int j = 0; j < 4; ++j)
                atomicAdd(&ctxT[(size_t)bh * 4096 + (e + j) * 64 + dd], acc2[tm][j]);
        }
    } else {
        // ---- generic epilogue ----
#pragma unroll
        for (int mi = 0; mi < 8; ++mi) {
            int row = m0 + wm * 128 + mi * 16 + ((l >> 4) << 2);
#pragma unroll
            for (int ni = 0; ni < 4; ++ni) {
                int col = n0 + wn * 64 + ni * 16 + (l & 15);
                float bv = BIAS ? bias[col] : 0.f;
#pragma unroll
                for (int j = 0; j < 4; ++j) {
                    float v = acc[mi][ni][j] + bv;
                    if (OUTF32) ((float*)Cout)[(size_t)(row + j) * N + col] = v;
                    else        ((u16t*)Cout)[(size_t)(row + j) * N + col] = f2bf(v);
                }
            }
        }
    }
}

// GEMM1: [16384,1024] x [1024,3072]; q cols -> qkv; kv blocks -> ctxT/ksum directly
__global__ __launch_bounds__(512, 2) void gemm_qkv(const u16t* __restrict__ A, const u16t* __restrict__ Bt,
                                                   u16t* __restrict__ C, float* __restrict__ ksum,
                                                   float* __restrict__ ctxT) {
    gemm256_body<0, 0, 0, 1>(A, Bt, C, nullptr, ksum, ctxT, 16384, 3072, 1024, 12, 1024);
}

// final: out[b] = qsm[b] (lda=3072, cols 0..1023) x W2T[b]^T + bias, f32
__global__ __launch_bounds__(512, 2) void gemm_out(const u16t* __restrict__ A, const u16t* __restrict__ Bt,
                                                   float* __restrict__ C, const float* __restrict__ bias) {
    gemm256_body<1, 1, 1, 0>(A, Bt, C, bias, nullptr, nullptr, 16384, 1024, 1024, 4, 3072);
}

// ---------------- q softmax (in-place over d=64, * SCALE) ----------------
// grid 1024, block 256; 8-lane groups, ushort8.
__global__ __launch_bounds__(256) void q_softmax_rows(u16t* __restrict__ qkv) {
    int t = threadIdx.x;
#pragma unroll
    for (int it = 0; it < 8; ++it) {
        int r = blockIdx.x * 256 + it * 32 + (t >> 3);
        size_t addr = (size_t)(r >> 4) * 3072 + (r & 15) * 64 + (t & 7) * 8;
        ushort8 ch = *(const ushort8*)(&qkv[addr]);
        float v0 = bf2f(ch[0]), v1 = bf2f(ch[1]), v2 = bf2f(ch[2]), v3 = bf2f(ch[3]);
        float v4 = bf2f(ch[4]), v5 = bf2f(ch[5]), v6 = bf2f(ch[6]), v7 = bf2f(ch[7]);
        float m = fmaxf(fmaxf(fmaxf(v0, v1), fmaxf(v2, v3)), fmaxf(fmaxf(v4, v5), fmaxf(v6, v7)));
        m = fmaxf(m, __shfl_xor(m, 1)); m = fmaxf(m, __shfl_xor(m, 2)); m = fmaxf(m, __shfl_xor(m, 4));
        float e0 = __expf(v0 - m), e1 = __expf(v1 - m), e2 = __expf(v2 - m), e3 = __expf(v3 - m);
        float e4 = __expf(v4 - m), e5 = __expf(v5 - m), e6 = __expf(v6 - m), e7 = __expf(v7 - m);
        float s = e0 + e1 + e2 + e3 + e4 + e5 + e6 + e7;
        s += __shfl_xor(s, 1); s += __shfl_xor(s, 2); s += __shfl_xor(s, 4);
        float inv = 0.125f / s;
        ushort8 o;
        o[0] = f2bf(e0 * inv); o[1] = f2bf(e1 * inv); o[2] = f2bf(e2 * inv); o[3] = f2bf(e3 * inv);
        o[4] = f2bf(e4 * inv); o[5] = f2bf(e5 * inv); o[6] = f2bf(e6 * inv); o[7] = f2bf(e7 * inv);
        *(ushort8*)(&qkv[addr]) = o;
    }
}

// ---------------- W2: W2T[b][j][h*64+d] = sum_e (ctxT[bh][e][d]/ksum[d]) * woutT[j][h*64+e] ----
__global__ __launch_bounds__(256) void w2_kernel(const float* __restrict__ ctxT,
                                                 const float* __restrict__ ksum,
                                                 const u16t* __restrict__ woutT,
                                                 u16t* __restrict__ w2t) {
    int bh = blockIdx.x, jc = blockIdx.y;
    int b = bh >> 4, h = bh & 15;
    __shared__ u16t cb[64][72];
    __shared__ u16t wl[256][72];
    int t = threadIdx.x;
    float ginv = 1.0f / ksum[b * 1024 + h * 64 + (t & 63)];   // f&63 == t&63 for all i
#pragma unroll
    for (int i = 0; i < 16; i++) {
        int f = t + 256 * i;
        cb[f & 63][f >> 6] = f2bf(ctxT[(size_t)bh * 4096 + f] * ginv);
    }
#pragma unroll
    for (int i = 0; i < 8; i++) {
        int f = t + 256 * i;
        int r = f >> 3, q = f & 7;
        *(uint4*)(&wl[r][q * 8]) = *(const uint4*)(&woutT[(size_t)(jc * 256 + r) * 1024 + h * 64 + q * 8]);
    }
    __syncthreads();
    int l = t & 63, w = t >> 6;
    f32x4 acc[4][4] = {};
#pragma unroll
    for (int kk = 0; kk < 2; kk++) {
        bf16x8 af[4], bfr[4];
#pragma unroll
        for (int mt = 0; mt < 4; mt++)
            af[mt] = *(const bf16x8*)&wl[w * 64 + mt * 16 + (l & 15)][(l >> 4) * 8 + kk * 32];
#pragma unroll
        for (int nt = 0; nt < 4; nt++)
            bfr[nt] = *(const bf16x8*)&cb[nt * 16 + (l & 15)][(l >> 4) * 8 + kk * 32];
#pragma unroll
        for (int mt = 0; mt < 4; mt++)
#pragma unroll
            for (int nt = 0; nt < 4; nt++)
                acc[mt][nt] = __builtin_amdgcn_mfma_f32_16x16x32_bf16(af[mt], bfr[nt], acc[mt][nt], 0, 0, 0);
    }
#pragma unroll
    for (int mt = 0; mt < 4; mt++) {
        int j = jc * 256 + w * 64 + mt * 16 + ((l >> 4) << 2);
#pragma unroll
        for (int nt = 0; nt < 4; nt++) {
            int dd = nt * 16 + (l & 15);
#pragma unroll
            for (int jj = 0; jj < 4; jj++)
                w2t[((size_t)b << 20) + (size_t)(j + jj) * 1024 + h * 64 + dd] = f2bf(acc[mt][nt][jj]);
        }
    }
}

// ---------------- launch ----------------

extern "C" void kernel_launch(void* const* d_in, const int* in_sizes, int n_in,
                              void* d_out, int out_size, void* d_ws, size_t ws_size,
                              hipStream_t stream) {
    const float* x     = (const float*)d_in[0];
    const float* w_qkv = (const float*)d_in[1];
    const float* w_out = (const float*)d_in[2];
    const float* b_out = (const float*)d_in[3];
    float* out = (float*)d_out;
    char* ws = (char*)d_ws;

    size_t o_xb    = 0;                       // 16384*1024*2 = 33554432 (reused as w2t)
    size_t o_wqkvT = 33554432;                // 3072*1024*2  = 6291456
    size_t o_woutT = 39845888;                // 1024*1024*2  = 2097152
    size_t o_qkv   = 41943040;                // 16384*3072*2 (q third used)
    size_t o_ctx   = 142606336;               // 64*64*64*4   = 1048576
    size_t o_ksum  = 143654912;               // 65536 (contiguous after ctx for zeroing)
    size_t needed  = 143720448;
    if (ws_size < needed) return;

    u16t* xb     = (u16t*)(ws + o_xb);
    u16t* w2t    = (u16t*)(ws + o_xb);        // reuse (xb dead after gemm_qkv)
    u16t* wqkvT  = (u16t*)(ws + o_wqkvT);
    u16t* woutT  = (u16t*)(ws + o_woutT);
    u16t* qkvb   = (u16t*)(ws + o_qkv);
    float* ctxT  = (float*)(ws + o_ctx);
    float* ksum  = (float*)(ws + o_ksum);

    // cvt + both weight transposes + zero(ctxT,ksum), one launch
    prep_kernel<<<6212, 256, 0, stream>>>(x, xb, w_qkv, wqkvT, w_out, woutT, ctxT);

    // GEMM1 + fused context: q cols -> qkv; kv blocks -> ctxT (unnorm) + ksum
    gemm_qkv<<<768, 512, 0, stream>>>(xb, wqkvT, qkvb, ksum, ctxT);

    // W2T[b][j][hd] = sum_e (ctx/ksum)[bh][e][d] * w_out[he][j]
    w2_kernel<<<dim3(64, 4), 256, 0, stream>>>(ctxT, ksum, woutT, w2t);

    // q softmax in-place
    q_softmax_rows<<<1024, 256, 0, stream>>>(qkvb);

    // out[b] = qsm[b] x W2T[b]^T + bias (f32)
    gemm_out<<<256, 512, 0, stream>>>(qkvb, w2t, out, b_out);
}